// Round 1
// baseline (74.866 us; speedup 1.0000x reference)
//
#include <hip/hip_runtime.h>
#include <hip/hip_bf16.h>

// ODECell: out[b][u] = Euler^6 of x' = -OMEGA*x + fA - x*fs, where
//   f[b,u,d] = sigmoid(sigma[u,d]*(inputs[b,d]-mu[u,d]))
//   fA = sum_d f*A[u,d], fs = sum_d f
// B=2048, U=128, D=128, all f32.

#define BATCH 2048
#define UNITS 128
#define IDIM  128
#define L2E   1.4426950408889634f

// ---------------- pre-pass: transpose inputs + precompute P,Q ----------------
// blocks [0,256): 32x32 transpose tiles of inputs (2048x128 -> 128x2048)
// blocks [256,320): P[i] = -L2E*sigma[i]; Q[i] = L2E*sigma[i]*mu[i]
__global__ __launch_bounds__(256) void ode_prep(
    const float* __restrict__ inputs,   // [B][D]
    const float* __restrict__ sigma,    // [U][D]
    const float* __restrict__ mu,       // [U][D]
    float* __restrict__ xT,             // [D][B]
    float* __restrict__ P,              // [U][D]
    float* __restrict__ Q)              // [U][D]
{
    const int bx  = blockIdx.x;
    const int tid = threadIdx.x;
    if (bx < 256) {
        // transpose tile: tileC in d (4 tiles), tileR in b (64 tiles)
        __shared__ float t[32][33];
        const int tileC = bx & 3;        // d tile
        const int tileR = bx >> 2;       // b tile
        const int c0 = tileC * 32, r0 = tileR * 32;
        const int tx = tid & 31, ty = tid >> 5;   // 32 x 8
        #pragma unroll
        for (int i = 0; i < 32; i += 8)
            t[ty + i][tx] = inputs[(r0 + ty + i) * IDIM + (c0 + tx)];
        __syncthreads();
        #pragma unroll
        for (int i = 0; i < 32; i += 8)
            xT[(c0 + ty + i) * BATCH + (r0 + tx)] = t[tx][ty + i];
    } else {
        const int i = (bx - 256) * 256 + tid;     // [0, 16384)
        const float s = sigma[i];
        P[i] = -L2E * s;
        Q[i] =  L2E * s * mu[i];
    }
}

// ---------------- main kernel ----------------
// 1024 blocks x 256 threads. Block = (b-tile of 64) x (4 u's, one per wave).
// lane = b_local -> coalesced xT loads; u wave-uniform -> s_load for P/Q/A.
__global__ __launch_bounds__(256) void ode_main(
    const float* __restrict__ xT,       // [D][B]
    const float* __restrict__ state,    // [B][U]
    const float* __restrict__ A,        // [U][D]
    const float* __restrict__ P,        // [U][D]
    const float* __restrict__ Q,        // [U][D]
    float* __restrict__ out)            // [B][U]
{
    const int tid  = threadIdx.x;
    const int lane = tid & 63;
    const int wave = tid >> 6;
    const int bx   = blockIdx.x;
    const int b    = (bx & 31) * 64 + lane;          // batch index
    int u          = (bx >> 5) * 4 + wave;           // unit index
    u = __builtin_amdgcn_readfirstlane(u);           // force SGPR -> s_load

    const float* __restrict__ Pu = P + u * IDIM;
    const float* __restrict__ Qu = Q + u * IDIM;
    const float* __restrict__ Au = A + u * IDIM;

    float fA0 = 0.f, fA1 = 0.f, fs0 = 0.f, fs1 = 0.f;
    #pragma unroll 8
    for (int d = 0; d < IDIM; d += 2) {
        const float x0 = xT[d * BATCH + b];
        const float x1 = xT[(d + 1) * BATCH + b];
        const float p0 = Pu[d],     q0 = Qu[d],     a0 = Au[d];
        const float p1 = Pu[d + 1], q1 = Qu[d + 1], a1 = Au[d + 1];
        const float e0 = __builtin_amdgcn_exp2f(fmaf(p0, x0, q0)); // exp(-sigma*(x-mu))
        const float e1 = __builtin_amdgcn_exp2f(fmaf(p1, x1, q1));
        const float f0 = __builtin_amdgcn_rcpf(1.0f + e0);         // sigmoid
        const float f1 = __builtin_amdgcn_rcpf(1.0f + e1);
        fA0 = fmaf(f0, a0, fA0);
        fA1 = fmaf(f1, a1, fA1);
        fs0 += f0;
        fs1 += f1;
    }
    const float fA = fA0 + fA1;
    const float fs = fs0 + fs1;

    float x = state[b * UNITS + u];
    const float dtu = (float)(0.1 / 6.0);
    const float ofs = 0.1f + fs;                     // OMEGA + fs
    #pragma unroll
    for (int k = 0; k < 6; ++k) {
        const float dx = fmaf(-x, ofs, fA);          // fA - x*(OMEGA+fs)
        x = fmaf(dtu, dx, x);
    }
    out[b * UNITS + u] = x;
}

extern "C" void kernel_launch(void* const* d_in, const int* in_sizes, int n_in,
                              void* d_out, int out_size, void* d_ws, size_t ws_size,
                              hipStream_t stream) {
    const float* inputs = (const float*)d_in[0];   // [B][D]
    const float* state  = (const float*)d_in[1];   // [B][U]
    const float* A      = (const float*)d_in[2];   // [U][D]
    const float* sigma  = (const float*)d_in[3];   // [U][D]
    const float* mu     = (const float*)d_in[4];   // [U][D]
    float* out = (float*)d_out;

    // ws layout: xT (1 MB) | P (64 KB) | Q (64 KB)
    float* xT = (float*)d_ws;
    float* P  = xT + BATCH * IDIM;
    float* Q  = P + UNITS * IDIM;

    ode_prep<<<320, 256, 0, stream>>>(inputs, sigma, mu, xT, P, Q);
    ode_main<<<1024, 256, 0, stream>>>(xT, state, A, P, Q, out);
}

// Round 4
// 70.505 us; speedup vs baseline: 1.0619x; 1.0619x over previous
//
#include <hip/hip_runtime.h>
#include <hip/hip_bf16.h>

// ODECell fused single kernel.
// out[b][u] = Euler^6 of x' = -OMEGA*x + fA - x*fs, where
//   f[b,u,d] = sigmoid(sigma[u,d]*(inputs[b,d]-mu[u,d]))
//   fA = sum_d f*A[u,d], fs = sum_d f
// B=2048, U=128, D=128, all f32.
//
// Block = 64 batches x 8 units, 256 threads (4 waves, 2 u per thread).
// inputs tile staged in padded LDS (transpose-free column reads),
// P=-log2e*sigma, Q=log2e*sigma*mu computed per block into LDS,
// A read via wave-uniform scalar loads. Grid 512 = 2 blocks/CU.

#define BATCH 2048
#define UNITS 128
#define IDIM  128
#define L2E   1.4426950408889634f

#define BTILE 64
#define UTILE 8
#define XPAD  132   // x-tile row stride in words: b128 reads land ~2-way (free)

__global__ __launch_bounds__(256) void ode_fused(
    const float* __restrict__ inputs,  // [B][D]
    const float* __restrict__ state,   // [B][U]
    const float* __restrict__ A,       // [U][D]
    const float* __restrict__ sigma,   // [U][D]
    const float* __restrict__ mu,      // [U][D]
    float* __restrict__ out)           // [B][U]
{
    __shared__ float  xl[BTILE * XPAD];   // 33792 B
    __shared__ float2 pq[UTILE][IDIM];    // 8192 B

    const int tid  = threadIdx.x;
    const int lane = tid & 63;
    const int wave = __builtin_amdgcn_readfirstlane(tid >> 6);
    const int bx   = blockIdx.x;
    const int b0   = (bx & 31) * BTILE;   // same b-tile -> same XCD (stride-32 grid)
    const int u0   = (bx >> 5) * UTILE;

    // ---- stage inputs tile (64 x 128 f32) into padded LDS, coalesced ----
    {
        const float4* in4 = (const float4*)(inputs + b0 * IDIM);
        const int c4 = tid & 31;
        int r = tid >> 5;
        #pragma unroll
        for (int k = 0; k < 8; ++k, r += 8) {
            float4 v = in4[r * (IDIM / 4) + c4];
            *(float4*)(xl + r * XPAD + c4 * 4) = v;
        }
    }
    // ---- P,Q for the block's 8 u's ----
    {
        #pragma unroll
        for (int k = 0; k < 4; ++k) {
            const int idx = k * 256 + tid;        // [0,1024)
            const int uu = idx >> 7, dd = idx & 127;
            const float s = sigma[(u0 + uu) * IDIM + dd];
            const float m = mu[(u0 + uu) * IDIM + dd];
            pq[uu][dd] = make_float2(-L2E * s, L2E * s * m);
        }
    }
    __syncthreads();

    const int la = wave * 2, lb = la + 1;         // local u indices
    const int ua = u0 + la, ub = u0 + lb;
    const float* __restrict__ Aa = A + ua * IDIM; // wave-uniform -> s_load
    const float* __restrict__ Ab = A + ub * IDIM;

    float fAa0 = 0.f, fAa1 = 0.f, fsa0 = 0.f, fsa1 = 0.f;
    float fAb0 = 0.f, fAb1 = 0.f, fsb0 = 0.f, fsb1 = 0.f;

    const float* xrow = xl + lane * XPAD;
    #pragma unroll 2
    for (int d = 0; d < IDIM; d += 4) {
        const float4 x4 = *(const float4*)(xrow + d);
        const float4 pa01 = *(const float4*)&pq[la][d];     // {p0,q0,p1,q1}
        const float4 pa23 = *(const float4*)&pq[la][d + 2];
        const float4 pb01 = *(const float4*)&pq[lb][d];
        const float4 pb23 = *(const float4*)&pq[lb][d + 2];
        const float4 a4a  = *(const float4*)(Aa + d);
        const float4 a4b  = *(const float4*)(Ab + d);

        const float fa0 = __builtin_amdgcn_rcpf(1.0f + __builtin_amdgcn_exp2f(fmaf(pa01.x, x4.x, pa01.y)));
        const float fa1 = __builtin_amdgcn_rcpf(1.0f + __builtin_amdgcn_exp2f(fmaf(pa01.z, x4.y, pa01.w)));
        const float fa2 = __builtin_amdgcn_rcpf(1.0f + __builtin_amdgcn_exp2f(fmaf(pa23.x, x4.z, pa23.y)));
        const float fa3 = __builtin_amdgcn_rcpf(1.0f + __builtin_amdgcn_exp2f(fmaf(pa23.z, x4.w, pa23.w)));
        const float fb0 = __builtin_amdgcn_rcpf(1.0f + __builtin_amdgcn_exp2f(fmaf(pb01.x, x4.x, pb01.y)));
        const float fb1 = __builtin_amdgcn_rcpf(1.0f + __builtin_amdgcn_exp2f(fmaf(pb01.z, x4.y, pb01.w)));
        const float fb2 = __builtin_amdgcn_rcpf(1.0f + __builtin_amdgcn_exp2f(fmaf(pb23.x, x4.z, pb23.y)));
        const float fb3 = __builtin_amdgcn_rcpf(1.0f + __builtin_amdgcn_exp2f(fmaf(pb23.z, x4.w, pb23.w)));

        fAa0 = fmaf(fa0, a4a.x, fAa0);  fAa1 = fmaf(fa1, a4a.y, fAa1);
        fAa0 = fmaf(fa2, a4a.z, fAa0);  fAa1 = fmaf(fa3, a4a.w, fAa1);
        fsa0 += fa0 + fa2;              fsa1 += fa1 + fa3;
        fAb0 = fmaf(fb0, a4b.x, fAb0);  fAb1 = fmaf(fb1, a4b.y, fAb1);
        fAb0 = fmaf(fb2, a4b.z, fAb0);  fAb1 = fmaf(fb3, a4b.w, fAb1);
        fsb0 += fb0 + fb2;              fsb1 += fb1 + fb3;
    }

    const float fA_a = fAa0 + fAa1, fs_a = fsa0 + fsa1;
    const float fA_b = fAb0 + fAb1, fs_b = fsb0 + fsb1;

    const int b = b0 + lane;
    float xa = state[b * UNITS + ua];
    float xb = state[b * UNITS + ub];
    const float dtu = (float)(0.1 / 6.0);
    const float ofa = 0.1f + fs_a;   // OMEGA + fs
    const float ofb = 0.1f + fs_b;
    #pragma unroll
    for (int k = 0; k < 6; ++k) {
        xa = fmaf(dtu, fmaf(-xa, ofa, fA_a), xa);
        xb = fmaf(dtu, fmaf(-xb, ofb, fA_b), xb);
    }
    out[b * UNITS + ua] = xa;
    out[b * UNITS + ub] = xb;
}

extern "C" void kernel_launch(void* const* d_in, const int* in_sizes, int n_in,
                              void* d_out, int out_size, void* d_ws, size_t ws_size,
                              hipStream_t stream) {
    const float* inputs = (const float*)d_in[0];
    const float* state  = (const float*)d_in[1];
    const float* A      = (const float*)d_in[2];
    const float* sigma  = (const float*)d_in[3];
    const float* mu     = (const float*)d_in[4];
    float* out = (float*)d_out;

    ode_fused<<<(BATCH / BTILE) * (UNITS / UTILE), 256, 0, stream>>>(
        inputs, state, A, sigma, mu, out);
}